// Round 1
// baseline (318.939 us; speedup 1.0000x reference)
//
#include <hip/hip_runtime.h>
#include <hip/hip_bf16.h>

// QuantizedConv2d: x[32,256,56,56] f32, q_weight[256,256,3,3] i32, w=q*s+m,
// conv 3x3 pad 1, + bias. Output f32 [32,256,56,56].
//
// Strategy: dequant weights to bf16 (w2[k9][o][i], i contiguous),
// transpose x to NHWC bf16 (xt[n][h*56+w][i]), then direct-conv with
// mfma_f32_16x16x32_bf16. A = weights (M=o), B = x patches (N=pixels).

typedef __bf16 bf16x8 __attribute__((ext_vector_type(8)));
typedef float floatx4 __attribute__((ext_vector_type(4)));

#define XT_ELEMS 25690112L  // 32*256*56*56

// ---------------- kernel 1: dequantize weights ----------------
// w2 layout: [k9=kh*3+kw][o][i], bf16.  589824 elements total (9*256*256).
__global__ void dequant_w(const int* __restrict__ q, const float* __restrict__ sp,
                          const float* __restrict__ mp, __hip_bfloat16* __restrict__ w2) {
  int idx = blockIdx.x * 256 + threadIdx.x;  // 0 .. 589823
  float s = sp[0], m = mp[0];
  int i = idx & 255;
  int o = (idx >> 8) & 255;
  int k9 = idx >> 16;  // 589824 = 9 * 65536, so k9 in 0..8
  float w = (float)q[(o * 256 + i) * 9 + k9] * s + m;
  w2[idx] = __float2bfloat16(w);
}

// ---------------- kernel 2: NCHW f32 -> NHWC bf16 ----------------
// x[n][c][p] (p = h*56+w, 3136 = 49*64) -> xt[n][p][c]
__global__ void transpose_x(const float* __restrict__ x, __hip_bfloat16* __restrict__ xt) {
  __shared__ float tile[64][68];  // pad 68 to avoid bank conflicts
  int n = blockIdx.z;
  int cb = blockIdx.y << 6;  // channel tile base (0,64,128,192)
  int pb = blockIdx.x << 6;  // pixel tile base (49 tiles)
  int t = threadIdx.x;

  const float* src = x + ((long)(n * 256 + cb)) * 3136 + pb;
#pragma unroll
  for (int it = 0; it < 4; it++) {
    int flat = it * 1024 + t * 4;
    int c = flat >> 6, p = flat & 63;
    float4 v = *(const float4*)(src + (long)c * 3136 + p);
    *(float4*)&tile[c][p] = v;
  }
  __syncthreads();
  __hip_bfloat16* dst = xt + ((long)(n * 3136 + pb)) * 256 + cb;
#pragma unroll
  for (int it = 0; it < 4; it++) {
    int flat = it * 1024 + t * 4;
    int p = flat >> 6, c = flat & 63;
    union {
      ushort4 u;
      __hip_bfloat16 h[4];
    } tmp;
#pragma unroll
    for (int j = 0; j < 4; j++) tmp.h[j] = __float2bfloat16(tile[c + j][p]);
    *(ushort4*)(dst + (long)p * 256 + c) = tmp.u;
  }
}

// ---------------- kernel 3: direct conv via MFMA ----------------
// Block tile: 128 output channels x 224 pixels (4 rows x 56 cols, exact).
// 4 waves: wave grid 2(o) x 2(px): each wave 64 o x 112 px = 4x7 mfma tiles.
// K loop: 8 channel blocks of 32, x 9 taps. x tile staged raw with halo:
// 6 rows x 58 cols x 32 ch, channel stride padded to 40 elems (80 B).
__global__ __launch_bounds__(256, 2) void conv_mfma(
    const __hip_bfloat16* __restrict__ xt, const __hip_bfloat16* __restrict__ w2,
    const float* __restrict__ bias, float* __restrict__ out) {
  __shared__ __align__(16) __hip_bfloat16 xs[6 * 58 * 40];  // 27840 B
  __shared__ __align__(16) __hip_bfloat16 wsh[128 * 40];    // 10240 B

  int ob = blockIdx.x;  // 0..1   o block
  int rb = blockIdx.y;  // 0..13  row block (4 rows each)
  int n = blockIdx.z;   // 0..31
  int t = threadIdx.x;
  int lane = t & 63;
  int wid = t >> 6;
  int wo = (wid & 1) << 6;       // wave o offset (0/64)
  int wpx = (wid >> 1) * 112;    // wave px offset (0/112)
  int l15 = lane & 15, quad = lane >> 4;
  int o0 = ob << 7;
  int h0 = rb << 2;

  // B-fragment LDS element bases, one per px tile (k chunk of this lane = quad*8)
  int baddr[7];
#pragma unroll
  for (int tt = 0; tt < 7; tt++) {
    int px = wpx + tt * 16 + l15;  // 0..223
    int r = px / 56, c = px - r * 56;
    baddr[tt] = (r * 58 + c) * 40 + quad * 8;  // element offset in xs
  }

  // x staging precompute: 6*58 (row,col) positions x 4 chunks of 16 B = 1392 chunks
  int xlds[6];  // LDS element offset, -1 = inactive
  int xgo[6];   // global element offset (without i0), -1 = zero-fill (halo)
#pragma unroll
  for (int it = 0; it < 6; it++) {
    int q = t + it * 256;
    xlds[it] = -1;
    xgo[it] = -1;
    if (q < 1392) {
      int pos = q >> 2, ck = q & 3;
      int row = pos / 58, col = pos - row * 58;
      int h = h0 - 1 + row, w = col - 1;
      bool v = (h >= 0) && (h < 56) && (w >= 0) && (w < 56);
      xlds[it] = pos * 40 + ck * 8;
      if (v) xgo[it] = (n * 3136 + h * 56 + w) * 256 + ck * 8;
    }
  }

  floatx4 acc[4][7];
#pragma unroll
  for (int m = 0; m < 4; m++)
#pragma unroll
    for (int tt = 0; tt < 7; tt++) acc[m][tt] = (floatx4){0.f, 0.f, 0.f, 0.f};

  for (int ib = 0; ib < 8; ib++) {
    int i0 = ib * 32;
    for (int k9 = 0; k9 < 9; k9++) {
      if (k9 == 0) {
        // stage x tile (halo included, zeros outside image)
#pragma unroll
        for (int it = 0; it < 6; it++) {
          if (xlds[it] >= 0) {
            int4 v = {0, 0, 0, 0};
            if (xgo[it] >= 0) v = *(const int4*)((const void*)(xt + xgo[it] + i0));
            *(int4*)((void*)(xs + xlds[it])) = v;
          }
        }
      }
      // stage weight tile [128 o][32 i] for this tap
      {
        int base = (k9 * 256 + o0) * 256 + i0;
#pragma unroll
        for (int it = 0; it < 2; it++) {
          int q2 = t + it * 256;  // 0..511 chunks of 16 B
          int o_r = q2 >> 2, ck = q2 & 3;
          int4 v = *(const int4*)((const void*)(w2 + base + o_r * 256 + ck * 8));
          *(int4*)((void*)(wsh + o_r * 40 + ck * 8)) = v;
        }
      }
      __syncthreads();

      int kh = k9 / 3, kw = k9 - kh * 3;
      int koff = (kh * 58 + kw) * 40;  // uniform tap shift in elements
      bf16x8 a[4];
#pragma unroll
      for (int m = 0; m < 4; m++)
        a[m] = *(const bf16x8*)((const void*)(wsh + (wo + m * 16 + l15) * 40 + quad * 8));
#pragma unroll
      for (int tt = 0; tt < 7; tt++) {
        bf16x8 b = *(const bf16x8*)((const void*)(xs + baddr[tt] + koff));
#pragma unroll
        for (int m = 0; m < 4; m++)
          acc[m][tt] = __builtin_amdgcn_mfma_f32_16x16x32_bf16(a[m], b, acc[m][tt], 0, 0, 0);
      }
      __syncthreads();
    }
  }

  // epilogue: C/D layout col=lane&15 (px), row=quad*4+reg (o)
#pragma unroll
  for (int m = 0; m < 4; m++) {
    int obase = o0 + wo + m * 16 + quad * 4;
#pragma unroll
    for (int r = 0; r < 4; r++) {
      int o = obase + r;
      float bv = bias[o];
      int outb = (n * 256 + o) * 3136 + h0 * 56;
#pragma unroll
      for (int tt = 0; tt < 7; tt++) {
        int px = wpx + tt * 16 + l15;
        out[outb + px] = acc[m][tt][r] + bv;
      }
    }
  }
}

extern "C" void kernel_launch(void* const* d_in, const int* in_sizes, int n_in,
                              void* d_out, int out_size, void* d_ws, size_t ws_size,
                              hipStream_t stream) {
  const float* x = (const float*)d_in[0];
  const int* qw = (const int*)d_in[1];
  const float* wscale = (const float*)d_in[2];
  const float* wmin = (const float*)d_in[3];
  const float* bias = (const float*)d_in[4];
  float* out = (float*)d_out;

  __hip_bfloat16* xt = (__hip_bfloat16*)d_ws;                        // 51,380,224 B
  __hip_bfloat16* w2 = (__hip_bfloat16*)((char*)d_ws + XT_ELEMS * 2);  // 1,179,648 B

  dequant_w<<<2304, 256, 0, stream>>>(qw, wscale, wmin, w2);
  transpose_x<<<dim3(49, 4, 32), 256, 0, stream>>>(x, xt);
  conv_mfma<<<dim3(2, 14, 32), 256, 0, stream>>>(xt, w2, bias, out);
}

// Round 2
// 318.241 us; speedup vs baseline: 1.0022x; 1.0022x over previous
//
#include <hip/hip_runtime.h>
#include <hip/hip_bf16.h>

// QuantizedConv2d: x[32,256,56,56] f32, q_weight[256,256,3,3] i32, w=q*s+m,
// conv 3x3 pad 1, + bias. Output f32 [32,256,56,56].
//
// v2: LDS-free register transpose (512B/wave coalesced stores), coalesced
// dequant, conv stages one kh-row of weights (3 taps) per barrier pair
// (24 barrier pairs instead of 144), halo zero-filled once.

typedef __bf16 bf16x8 __attribute__((ext_vector_type(8)));
typedef float floatx4 __attribute__((ext_vector_type(4)));

#define XT_ELEMS 25690112L  // 32*256*56*56

// ---------------- kernel 1: dequantize weights ----------------
// w2 layout: [k9=kh*3+kw][o][i], bf16. One thread per (o,i) pair.
// Reads 9 contiguous ints (36B, coalesced across lanes); 9 coalesced 2B stores.
__global__ void dequant_w(const int* __restrict__ q, const float* __restrict__ sp,
                          const float* __restrict__ mp, __hip_bfloat16* __restrict__ w2) {
  int g = blockIdx.x * 256 + threadIdx.x;  // 0 .. 65535 = o*256+i
  float s = sp[0], m = mp[0];
  const int* qp = q + (long)g * 9;
#pragma unroll
  for (int j = 0; j < 9; j++) {
    float w = (float)qp[j] * s + m;
    w2[(long)j * 65536 + g] = __float2bfloat16(w);
  }
}

// ---------------- kernel 2: NCHW f32 -> NHWC bf16, LDS-free ----------------
// Block: 64 px x 256 ch. Thread: 4 ch x 16 px. Each thread's 4 pi-loads of a
// channel cover one full 64B line (L1 reuse); stores: wave writes one
// contiguous 512B pixel row (64 lanes x ushort4).
__global__ __launch_bounds__(256) void transpose_x(const float* __restrict__ x,
                                                   __hip_bfloat16* __restrict__ xt) {
  int n = blockIdx.y;
  int pb = blockIdx.x << 6;
  int t = threadIdx.x;
  int c0 = (t & 63) << 2;   // channel base, 4 channels per thread
  int p0 = (t >> 6) << 4;   // pixel base, 16 px per thread

  const float* src = x + (long)n * 802816 + pb;
  __hip_bfloat16* dst = xt + ((long)(n * 3136 + pb)) * 256;

#pragma unroll
  for (int pi = 0; pi < 4; pi++) {
    int p = p0 + pi * 4;
    float v[4][4];
#pragma unroll
    for (int cj = 0; cj < 4; cj++)
      *(float4*)v[cj] = *(const float4*)(src + (long)(c0 + cj) * 3136 + p);
#pragma unroll
    for (int j = 0; j < 4; j++) {
      union {
        ushort4 u;
        __hip_bfloat16 h[4];
      } r;
#pragma unroll
      for (int cj = 0; cj < 4; cj++) r.h[cj] = __float2bfloat16(v[cj][j]);
      *(ushort4*)(dst + (long)(p + j) * 256 + c0) = r.u;
    }
  }
}

// ---------------- kernel 3: direct conv via MFMA ----------------
// Block tile: 128 o x 224 px (4 rows x 56 cols, exact). 4 waves (2o x 2px),
// each wave 64 o x 112 px = 4x7 mfma 16x16x32 tiles.
// K loop: 8 channel blocks of 32 x 3 kh rows; per barrier pair we stage
// 3 taps of weights (and x tile when kh==0), then run 84 MFMAs.
__global__ __launch_bounds__(256, 2) void conv_mfma(
    const __hip_bfloat16* __restrict__ xt, const __hip_bfloat16* __restrict__ w2,
    const float* __restrict__ bias, float* __restrict__ out) {
  __shared__ __align__(16) __hip_bfloat16 xs[6 * 58 * 40];     // 27840 B
  __shared__ __align__(16) __hip_bfloat16 wsh[3 * 128 * 40];   // 30720 B

  int ob = blockIdx.x;  // 0..1   o block
  int rb = blockIdx.y;  // 0..13  row block (4 rows each)
  int n = blockIdx.z;   // 0..31
  int t = threadIdx.x;
  int lane = t & 63;
  int wid = t >> 6;
  int wo = (wid & 1) << 6;     // wave o offset (0/64)
  int wpx = (wid >> 1) * 112;  // wave px offset (0/112)
  int l15 = lane & 15, quad = lane >> 4;
  int o0 = ob << 7;
  int h0 = rb << 2;

  // B-fragment LDS element bases, one per px tile
  int baddr[7];
#pragma unroll
  for (int tt = 0; tt < 7; tt++) {
    int px = wpx + tt * 16 + l15;  // 0..223
    int r = px / 56, c = px - r * 56;
    baddr[tt] = (r * 58 + c) * 40 + quad * 8;
  }

  // x staging precompute: 6*58 positions x 4 chunks of 16B = 1392 chunks
  int xlds[6];  // LDS element offset, -1 = inactive
  int xgo[6];   // global element offset (without i0), -1 = halo (stays zero)
#pragma unroll
  for (int it = 0; it < 6; it++) {
    int q = t + it * 256;
    xlds[it] = -1;
    xgo[it] = -1;
    if (q < 1392) {
      int pos = q >> 2, ck = q & 3;
      int row = pos / 58, col = pos - row * 58;
      int h = h0 - 1 + row, w = col - 1;
      bool v = (h >= 0) && (h < 56) && (w >= 0) && (w < 56);
      xlds[it] = pos * 40 + ck * 8;
      if (v) xgo[it] = (n * 3136 + h * 56 + w) * 256 + ck * 8;
    }
  }

  // zero halo cells once (never rewritten afterwards)
#pragma unroll
  for (int it = 0; it < 6; it++)
    if (xlds[it] >= 0 && xgo[it] < 0) *(int4*)((void*)(xs + xlds[it])) = (int4){0, 0, 0, 0};

  floatx4 acc[4][7];
#pragma unroll
  for (int m = 0; m < 4; m++)
#pragma unroll
    for (int tt = 0; tt < 7; tt++) acc[m][tt] = (floatx4){0.f, 0.f, 0.f, 0.f};

  for (int ib = 0; ib < 8; ib++) {
    int i0 = ib * 32;
    for (int kh = 0; kh < 3; kh++) {
      __syncthreads();  // previous compute done before overwrite
      if (kh == 0) {
#pragma unroll
        for (int it = 0; it < 6; it++)
          if (xgo[it] >= 0)
            *(int4*)((void*)(xs + xlds[it])) = *(const int4*)((const void*)(xt + xgo[it] + i0));
      }
      // stage weights for taps kh*3 + {0,1,2}: 3*128 rows x 32 i = 1536 chunks
#pragma unroll
      for (int it = 0; it < 6; it++) {
        int q2 = t + it * 256;  // 0..1535
        int tap = q2 >> 9;
        int rem = q2 & 511;
        int o_r = rem >> 2, ck = rem & 3;
        int4 v = *(const int4*)((const void*)(
            w2 + ((long)(kh * 3 + tap) * 256 + o0 + o_r) * 256 + i0 + ck * 8));
        *(int4*)((void*)(wsh + (tap * 128 + o_r) * 40 + ck * 8)) = v;
      }
      __syncthreads();

#pragma unroll
      for (int kw = 0; kw < 3; kw++) {
        int koff = (kh * 58 + kw) * 40;
        bf16x8 a[4];
#pragma unroll
        for (int m = 0; m < 4; m++)
          a[m] = *(const bf16x8*)((const void*)(wsh + (kw * 128 + wo + m * 16 + l15) * 40 + quad * 8));
#pragma unroll
        for (int tt = 0; tt < 7; tt++) {
          bf16x8 b = *(const bf16x8*)((const void*)(xs + baddr[tt] + koff));
#pragma unroll
          for (int m = 0; m < 4; m++)
            acc[m][tt] = __builtin_amdgcn_mfma_f32_16x16x32_bf16(a[m], b, acc[m][tt], 0, 0, 0);
        }
      }
    }
  }

  // epilogue: C/D layout col=lane&15 (px), row=quad*4+reg (o)
#pragma unroll
  for (int m = 0; m < 4; m++) {
    int obase = o0 + wo + m * 16 + quad * 4;
#pragma unroll
    for (int r = 0; r < 4; r++) {
      int o = obase + r;
      float bv = bias[o];
      int outb = (n * 256 + o) * 3136 + h0 * 56;
#pragma unroll
      for (int tt = 0; tt < 7; tt++) {
        int px = wpx + tt * 16 + l15;
        out[outb + px] = acc[m][tt][r] + bv;
      }
    }
  }
}

extern "C" void kernel_launch(void* const* d_in, const int* in_sizes, int n_in,
                              void* d_out, int out_size, void* d_ws, size_t ws_size,
                              hipStream_t stream) {
  const float* x = (const float*)d_in[0];
  const int* qw = (const int*)d_in[1];
  const float* wscale = (const float*)d_in[2];
  const float* wmin = (const float*)d_in[3];
  const float* bias = (const float*)d_in[4];
  float* out = (float*)d_out;

  __hip_bfloat16* xt = (__hip_bfloat16*)d_ws;                          // 51,380,224 B
  __hip_bfloat16* w2 = (__hip_bfloat16*)((char*)d_ws + XT_ELEMS * 2);  // 1,179,648 B

  dequant_w<<<256, 256, 0, stream>>>(qw, wscale, wmin, w2);
  transpose_x<<<dim3(49, 32), 256, 0, stream>>>(x, xt);
  conv_mfma<<<dim3(2, 14, 32), 256, 0, stream>>>(xt, w2, bias, out);
}